// Round 6
// baseline (141.824 us; speedup 1.0000x reference)
//
#include <hip/hip_runtime.h>

// Graph transformer block, exploiting multiplicative adjacency masking:
//   out_i = (Vsum + sum_edges (e^{s}-1) V_j) / (N + sum_edges (e^{s}-1))
// v6: adj_scan uses PLAIN cached loads (nontemporal suspected of capping read
//     BW at ~2.4 TB/s across r2/r4/r5) and compacts via LDS so the streaming
//     vmcnt FIFO contains only the row loads + one coalesced flush store.

#define NN  8192
#define DIM 256
#define SCALE 0.0625f   // 1/sqrt(256)
#define CAP 96          // per-segment edge capacity (mean 20.5, sd 4.5)
#define RPA 8           // rows per block in adj_scan

typedef __attribute__((ext_vector_type(8))) short short8;
typedef __attribute__((ext_vector_type(4))) float f32x4;
typedef __attribute__((ext_vector_type(4))) unsigned int u32x4;

__device__ __forceinline__ unsigned short f2bf(float f) {
    union { float f; unsigned u; } v; v.f = f;
    unsigned u = v.u;
    unsigned r = (u + 0x7fffu + ((u >> 16) & 1u)) >> 16;   // RNE
    return (unsigned short)r;
}
__device__ __forceinline__ float bf2f(unsigned short s) {
    union { unsigned u; float f; } v; v.u = ((unsigned)s) << 16;
    return v.f;
}
__device__ __forceinline__ float dw_lo(unsigned u) {
    union { unsigned u; float f; } v; v.u = u << 16; return v.f;
}
__device__ __forceinline__ float dw_hi(unsigned u) {
    union { unsigned u; float f; } v; v.u = u & 0xffff0000u; return v.f;
}

// ---------------------------------------------------------------- prep: fp32 -> bf16
__global__ __launch_bounds__(256) void prep_kernel(
    const float* __restrict__ h, const float* __restrict__ Wq,
    const float* __restrict__ Wk, const float* __restrict__ Wv,
    unsigned short* __restrict__ h_bf, unsigned short* __restrict__ w_bf)
{
    int b = blockIdx.x, t = threadIdx.x;
    if (b < 2048) {
        int idx = (b * 256 + t) * 4;               // h: 2,097,152 elems
        float4 v = *(const float4*)(h + idx);
        ushort4 o; o.x = f2bf(v.x); o.y = f2bf(v.y); o.z = f2bf(v.z); o.w = f2bf(v.w);
        *(ushort4*)(h_bf + idx) = o;
    } else {
        int idx = ((b - 2048) * 256 + t) * 4;      // W: 196,608 elems (3 x 65536)
        int w = idx >> 16;
        int offn = idx & 65535;
        const float* src = (w == 0) ? Wq : (w == 1) ? Wk : Wv;
        float4 v = *(const float4*)(src + offn);
        ushort4 o; o.x = f2bf(v.x); o.y = f2bf(v.y); o.z = f2bf(v.z); o.w = f2bf(v.w);
        *(ushort4*)(w_bf + idx) = o;
    }
}

// ---------------------------------------------------------------- projections via bf16 MFMA
__global__ __launch_bounds__(256) void proj_gemm(
    const unsigned short* __restrict__ h_bf, const unsigned short* __restrict__ w_bf,
    float* __restrict__ Q, unsigned short* __restrict__ Kb, unsigned short* __restrict__ Vb)
{
    __shared__ unsigned short sB[256][40];
    const int mb = blockIdx.x, p = blockIdx.y;
    const unsigned short* W = w_bf + (p << 16);
    const int tid = threadIdx.x, wave = tid >> 6, lane = tid & 63;

    f32x4 acc[16];
#pragma unroll
    for (int f = 0; f < 16; ++f) acc[f] = (f32x4)(0.0f);

    const int arow = mb * 64 + wave * 16 + (lane & 15);
    const int ko   = (lane >> 4) * 8;

    for (int kk = 0; kk < 256; kk += 32) {
        __syncthreads();
        {
            const uint4* src = (const uint4*)(W + tid * 256 + kk);
            uint4* dst = (uint4*)(&sB[tid][0]);
            dst[0] = src[0]; dst[1] = src[1]; dst[2] = src[2]; dst[3] = src[3];
        }
        __syncthreads();
        short8 a = *(const short8*)(h_bf + (size_t)arow * 256 + kk + ko);
#pragma unroll
        for (int f = 0; f < 16; ++f) {
            short8 b = *(const short8*)(&sB[f * 16 + (lane & 15)][ko]);
            acc[f] = __builtin_amdgcn_mfma_f32_16x16x32_bf16(a, b, acc[f], 0, 0, 0);
        }
    }

    const int orow = mb * 64 + wave * 16 + ((lane >> 4) << 2);
    const int ocol = lane & 15;
    if (p == 0) {
#pragma unroll
        for (int f = 0; f < 16; ++f)
#pragma unroll
            for (int r = 0; r < 4; ++r)
                Q[(size_t)(orow + r) * 256 + f * 16 + ocol] = acc[f][r];
    } else {
        unsigned short* dstb = (p == 1) ? Kb : Vb;
#pragma unroll
        for (int f = 0; f < 16; ++f)
#pragma unroll
            for (int r = 0; r < 4; ++r)
                dstb[(size_t)(orow + r) * 256 + f * 16 + ocol] = f2bf(acc[f][r]);
    }
}

// ---------------------------------------------------------------- Vsum = column sums of V
__global__ __launch_bounds__(256) void vsum_partial(
    const unsigned short* __restrict__ Vb, float* __restrict__ partial)
{
    int b = blockIdx.x, t = threadIdx.x;
    float s = 0.0f;
    for (int r = 0; r < 64; ++r)
        s += bf2f(Vb[(size_t)(b * 64 + r) * 256 + t]);
    partial[b * 256 + t] = s;
}
__global__ __launch_bounds__(256) void vsum_final(
    const float* __restrict__ partial, float* __restrict__ Vsum)
{
    int t = threadIdx.x;
    float s = 0.0f;
    for (int b = 0; b < 128; ++b) s += partial[b * 256 + t];
    Vsum[t] = s;
}

// ---------------------------------------------------------------- adj_scan (pure stream)
// 1024 blocks x 4 waves; wave w owns cols [w*2048, (w+1)*2048) of each row.
// 8 rows/block, avA/avB register ping-pong (compacting row r leaves row r+1's
// loads in flight). Compaction scatters into LDS (lgkmcnt domain), then one
// coalesced 192 B dword flush per row-segment -> the vmcnt FIFO holds almost
// exclusively the stream loads. Plain cached loads (no nontemporal).
#define LOADROW(av, row)                                                              \
    {                                                                                 \
        const f32x4* ar_ = (const f32x4*)(adj + (size_t)(row) * NN);                  \
        _Pragma("unroll")                                                             \
        for (int it_ = 0; it_ < 8; ++it_)                                             \
            av[it_] = ar_[pw * 512 + it_ * 64 + lane];                                \
    }

#define COMPACT_L(av, row)                                                            \
    {                                                                                 \
        int off_ = 0;                                                                 \
        _Pragma("unroll")                                                             \
        for (int it_ = 0; it_ < 8; ++it_) {                                           \
            const int colbase_ = (pw * 512 + it_ * 64 + lane) * 4;                    \
            _Pragma("unroll")                                                         \
            for (int c_ = 0; c_ < 4; ++c_) {                                          \
                bool nz_ = (av[it_][c_] != 0.0f);                                     \
                unsigned long long m_ = __ballot(nz_);                                \
                if (nz_) s_buf[pw][off_ + __popcll(m_ & lt)] = (unsigned short)(colbase_ + c_); \
                off_ += __popcll(m_);                                                 \
            }                                                                         \
        }                                                                             \
        if (lane < (CAP / 2)) {                                                       \
            unsigned w_ = ((const unsigned*)&s_buf[pw][0])[lane];                     \
            ((unsigned*)(eidx + ((size_t)(row) * 4 + pw) * CAP))[lane] = w_;          \
        }                                                                             \
        if (lane == 0) ecnt[(row) * 4 + pw] = off_;                                   \
    }

__global__ __launch_bounds__(256) void adj_scan(
    const float* __restrict__ adj,
    unsigned short* __restrict__ eidx, int* __restrict__ ecnt)
{
    __shared__ unsigned short s_buf[4][CAP];
    const int lane = threadIdx.x & 63;
    const int pw   = threadIdx.x >> 6;           // wave id = segment id
    const int r0   = blockIdx.x * RPA;
    const unsigned long long lt = (1ull << lane) - 1ull;

    f32x4 avA[8], avB[8];
    LOADROW(avA, r0);
    LOADROW(avB, r0 + 1);

#pragma unroll
    for (int rr = 0; rr < RPA; rr += 2) {
        COMPACT_L(avA, r0 + rr);                 // waits avA loads; avB stays in flight
        if (rr + 2 < RPA) LOADROW(avA, r0 + rr + 2);
        COMPACT_L(avB, r0 + rr + 1);             // waits avB; new avA stays in flight
        if (rr + 3 < RPA) LOADROW(avB, r0 + rr + 3);
    }
}

// ---------------------------------------------------------------- attn_edges
// One block per row. Stage u16 edge lists to LDS, then the round-2 fused loop:
// 16-lane group per edge dot, full-wave axpy of 4 V rows per round.
__global__ __launch_bounds__(256) void attn_edges(
    const unsigned short* __restrict__ eidx, const int* __restrict__ ecnt,
    const float* __restrict__ Q,
    const unsigned short* __restrict__ Kb, const unsigned short* __restrict__ Vb,
    const float* __restrict__ Vsum, float* __restrict__ out)
{
    __shared__ unsigned short s_idx[4][CAP];
    __shared__ float s_pacc[4][256];
    __shared__ float s_den[4];

    const int i    = blockIdx.x;
    const int tid  = threadIdx.x;
    const int lane = tid & 63;
    const int pw   = tid >> 6;

    // stage this wave's segment (96 u16 = 48 u32, one load per lane<48)
    const int cnt = ecnt[i * 4 + pw];
    {
        const unsigned* src = (const unsigned*)(eidx + ((size_t)i * 4 + pw) * CAP);
        if (lane < 48) ((unsigned*)&s_idx[pw][0])[lane] = src[lane];
    }

    const float* Qi = Q + (size_t)i * DIM + (lane & 15) * 16;
    f32x4 q0 = *(const f32x4*)(Qi);
    f32x4 q1 = *(const f32x4*)(Qi + 4);
    f32x4 q2 = *(const f32x4*)(Qi + 8);
    f32x4 q3 = *(const f32x4*)(Qi + 12);

    const int g = lane >> 4;
    float acc0 = 0.f, acc1 = 0.f, acc2 = 0.f, acc3 = 0.f, den = 0.f;
    const int rounds = (cnt + 3) >> 2;

#pragma unroll 2
    for (int r = 0; r < rounds; ++r) {
        const int kb0 = r * 4;
        int jg0 = (kb0 + 0 < cnt) ? (int)s_idx[pw][kb0 + 0] : 0;
        int jg1 = (kb0 + 1 < cnt) ? (int)s_idx[pw][kb0 + 1] : 0;
        int jg2 = (kb0 + 2 < cnt) ? (int)s_idx[pw][kb0 + 2] : 0;
        int jg3 = (kb0 + 3 < cnt) ? (int)s_idx[pw][kb0 + 3] : 0;

        const bool myv = (kb0 + g) < cnt;
        const int  myj = (g == 0) ? jg0 : (g == 1) ? jg1 : (g == 2) ? jg2 : jg3;

        const u32x4* kp = (const u32x4*)(Kb + (size_t)myj * DIM + (lane & 15) * 16);
        u32x4 ka = kp[0];
        u32x4 kc = kp[1];

        ushort4 v0 = *(const ushort4*)(Vb + (size_t)jg0 * DIM + lane * 4);
        ushort4 v1 = *(const ushort4*)(Vb + (size_t)jg1 * DIM + lane * 4);
        ushort4 v2 = *(const ushort4*)(Vb + (size_t)jg2 * DIM + lane * 4);
        ushort4 v3 = *(const ushort4*)(Vb + (size_t)jg3 * DIM + lane * 4);

        float d0 = q0[0] * dw_lo(ka[0]);
        float d1 = q0[1] * dw_hi(ka[0]);
        float d2 = q0[2] * dw_lo(ka[1]);
        float d3 = q0[3] * dw_hi(ka[1]);
        d0 = fmaf(q1[0], dw_lo(ka[2]), d0);
        d1 = fmaf(q1[1], dw_hi(ka[2]), d1);
        d2 = fmaf(q1[2], dw_lo(ka[3]), d2);
        d3 = fmaf(q1[3], dw_hi(ka[3]), d3);
        d0 = fmaf(q2[0], dw_lo(kc[0]), d0);
        d1 = fmaf(q2[1], dw_hi(kc[0]), d1);
        d2 = fmaf(q2[2], dw_lo(kc[1]), d2);
        d3 = fmaf(q2[3], dw_hi(kc[1]), d3);
        d0 = fmaf(q3[0], dw_lo(kc[2]), d0);
        d1 = fmaf(q3[1], dw_hi(kc[2]), d1);
        d2 = fmaf(q3[2], dw_lo(kc[3]), d2);
        d3 = fmaf(q3[3], dw_hi(kc[3]), d3);
        float d = (d0 + d1) + (d2 + d3);

        d += __shfl_xor(d, 1);
        d += __shfl_xor(d, 2);
        d += __shfl_xor(d, 4);
        d += __shfl_xor(d, 8);

        float e = myv ? (__expf(SCALE * d) - 1.0f) : 0.0f;

        float e0 = __shfl(e, 0);
        float e1 = __shfl(e, 16);
        float e2 = __shfl(e, 32);
        float e3 = __shfl(e, 48);
        den += (e0 + e1) + (e2 + e3);

        acc0 = fmaf(e0, bf2f(v0.x), acc0); acc1 = fmaf(e0, bf2f(v0.y), acc1);
        acc2 = fmaf(e0, bf2f(v0.z), acc2); acc3 = fmaf(e0, bf2f(v0.w), acc3);
        acc0 = fmaf(e1, bf2f(v1.x), acc0); acc1 = fmaf(e1, bf2f(v1.y), acc1);
        acc2 = fmaf(e1, bf2f(v1.z), acc2); acc3 = fmaf(e1, bf2f(v1.w), acc3);
        acc0 = fmaf(e2, bf2f(v2.x), acc0); acc1 = fmaf(e2, bf2f(v2.y), acc1);
        acc2 = fmaf(e2, bf2f(v2.z), acc2); acc3 = fmaf(e2, bf2f(v2.w), acc3);
        acc0 = fmaf(e3, bf2f(v3.x), acc0); acc1 = fmaf(e3, bf2f(v3.y), acc1);
        acc2 = fmaf(e3, bf2f(v3.z), acc2); acc3 = fmaf(e3, bf2f(v3.w), acc3);
    }

    f32x4 accv = {acc0, acc1, acc2, acc3};
    *(f32x4*)(&s_pacc[pw][lane * 4]) = accv;
    if (lane == 0) s_den[pw] = den;
    __syncthreads();

    float a  = (s_pacc[0][tid] + s_pacc[1][tid]) + (s_pacc[2][tid] + s_pacc[3][tid]);
    float dn = (s_den[0] + s_den[1]) + (s_den[2] + s_den[3]);
    out[(size_t)i * DIM + tid] = (Vsum[tid] + a) / (8192.0f + dn);
}

// ---------------------------------------------------------------- host
extern "C" void kernel_launch(void* const* d_in, const int* in_sizes, int n_in,
                              void* d_out, int out_size, void* d_ws, size_t ws_size,
                              hipStream_t stream)
{
    const float* adj = (const float*)d_in[0];
    const float* h   = (const float*)d_in[1];
    const float* Wq  = (const float*)d_in[2];
    const float* Wk  = (const float*)d_in[3];
    const float* Wv  = (const float*)d_in[4];
    float* out = (float*)d_out;

    char* ws = (char*)d_ws;
    size_t off = 0;
    unsigned short* p_hbf = (unsigned short*)(ws + off); off += (size_t)NN * DIM * 2;
    unsigned short* p_wbf = (unsigned short*)(ws + off); off += (size_t)3 * DIM * DIM * 2;
    off = (off + 1023) & ~(size_t)1023;
    float*          p_Q   = (float*)(ws + off);          off += (size_t)NN * DIM * 4;
    unsigned short* p_Kb  = (unsigned short*)(ws + off); off += (size_t)NN * DIM * 2;
    unsigned short* p_Vb  = (unsigned short*)(ws + off); off += (size_t)NN * DIM * 2;
    float*          p_par = (float*)(ws + off);          off += (size_t)128 * DIM * 4;
    float*          p_vs  = (float*)(ws + off);          off += DIM * 4;
    unsigned short* p_ei  = (unsigned short*)(ws + off); off += (size_t)NN * 4 * CAP * 2;
    int*            p_ec  = (int*)(ws + off);            off += (size_t)NN * 4 * 4;
    (void)ws_size; (void)in_sizes; (void)n_in; (void)out_size;

    adj_scan<<<NN / RPA, 256, 0, stream>>>(adj, p_ei, p_ec);
    prep_kernel<<<2240, 256, 0, stream>>>(h, Wq, Wk, Wv, p_hbf, p_wbf);
    proj_gemm<<<dim3(128, 3), 256, 0, stream>>>(p_hbf, p_wbf, p_Q, p_Kb, p_Vb);
    vsum_partial<<<128, 256, 0, stream>>>(p_Vb, p_par);
    vsum_final<<<1, 256, 0, stream>>>(p_par, p_vs);
    attn_edges<<<NN, 256, 0, stream>>>(p_ei, p_ec, p_Q, p_Kb, p_Vb, p_vs, out);
}

// Round 8
// 130.834 us; speedup vs baseline: 1.0840x; 1.0840x over previous
//
#include <hip/hip_runtime.h>

// Graph transformer block, exploiting multiplicative adjacency masking:
//   out_i = (Vsum + sum_edges (e^{s}-1) V_j) / (N + sum_edges (e^{s}-1))
// v8: fused scan+gather with XCD column-quadrant pinning.
//   Block b = (row i = b>>2, quadrant q = b&3) -> XCD x sees only q = x&3,
//   so each XCD's gather set is 2 MB of bf16 K/V (L2-resident). adj/Q/partial
//   streams are nontemporal so they don't evict the hot K/V slice. Per-row
//   quadrant partials (bf16 num + f32 den) are combined by a finalize kernel.

#define NN  8192
#define DIM 256
#define SCALE 0.0625f   // 1/sqrt(256)
#define CAP 64          // per-wave 512-col sub-slice capacity (mean 5.1)

typedef __attribute__((ext_vector_type(8))) short short8;
typedef __attribute__((ext_vector_type(4))) float f32x4;
typedef __attribute__((ext_vector_type(4))) unsigned int u32x4;

__device__ __forceinline__ unsigned short f2bf(float f) {
    union { float f; unsigned u; } v; v.f = f;
    unsigned u = v.u;
    unsigned r = (u + 0x7fffu + ((u >> 16) & 1u)) >> 16;   // RNE
    return (unsigned short)r;
}
__device__ __forceinline__ float bf2f(unsigned short s) {
    union { unsigned u; float f; } v; v.u = ((unsigned)s) << 16;
    return v.f;
}
__device__ __forceinline__ float dw_lo(unsigned u) {
    union { unsigned u; float f; } v; v.u = u << 16; return v.f;
}
__device__ __forceinline__ float dw_hi(unsigned u) {
    union { unsigned u; float f; } v; v.u = u & 0xffff0000u; return v.f;
}

// ---------------------------------------------------------------- prep: fp32 -> bf16
__global__ __launch_bounds__(256) void prep_kernel(
    const float* __restrict__ h, const float* __restrict__ Wq,
    const float* __restrict__ Wk, const float* __restrict__ Wv,
    unsigned short* __restrict__ h_bf, unsigned short* __restrict__ w_bf)
{
    int b = blockIdx.x, t = threadIdx.x;
    if (b < 2048) {
        int idx = (b * 256 + t) * 4;               // h: 2,097,152 elems
        float4 v = *(const float4*)(h + idx);
        ushort4 o; o.x = f2bf(v.x); o.y = f2bf(v.y); o.z = f2bf(v.z); o.w = f2bf(v.w);
        *(ushort4*)(h_bf + idx) = o;
    } else {
        int idx = ((b - 2048) * 256 + t) * 4;      // W: 196,608 elems (3 x 65536)
        int w = idx >> 16;
        int offn = idx & 65535;
        const float* src = (w == 0) ? Wq : (w == 1) ? Wk : Wv;
        float4 v = *(const float4*)(src + offn);
        ushort4 o; o.x = f2bf(v.x); o.y = f2bf(v.y); o.z = f2bf(v.z); o.w = f2bf(v.w);
        *(ushort4*)(w_bf + idx) = o;
    }
}

// ---------------------------------------------------------------- projections via bf16 MFMA
__global__ __launch_bounds__(256) void proj_gemm(
    const unsigned short* __restrict__ h_bf, const unsigned short* __restrict__ w_bf,
    float* __restrict__ Q, unsigned short* __restrict__ Kb, unsigned short* __restrict__ Vb)
{
    __shared__ unsigned short sB[256][40];
    const int mb = blockIdx.x, p = blockIdx.y;
    const unsigned short* W = w_bf + (p << 16);
    const int tid = threadIdx.x, wave = tid >> 6, lane = tid & 63;

    f32x4 acc[16];
#pragma unroll
    for (int f = 0; f < 16; ++f) acc[f] = (f32x4)(0.0f);

    const int arow = mb * 64 + wave * 16 + (lane & 15);
    const int ko   = (lane >> 4) * 8;

    for (int kk = 0; kk < 256; kk += 32) {
        __syncthreads();
        {
            const uint4* src = (const uint4*)(W + tid * 256 + kk);
            uint4* dst = (uint4*)(&sB[tid][0]);
            dst[0] = src[0]; dst[1] = src[1]; dst[2] = src[2]; dst[3] = src[3];
        }
        __syncthreads();
        short8 a = *(const short8*)(h_bf + (size_t)arow * 256 + kk + ko);
#pragma unroll
        for (int f = 0; f < 16; ++f) {
            short8 b = *(const short8*)(&sB[f * 16 + (lane & 15)][ko]);
            acc[f] = __builtin_amdgcn_mfma_f32_16x16x32_bf16(a, b, acc[f], 0, 0, 0);
        }
    }

    const int orow = mb * 64 + wave * 16 + ((lane >> 4) << 2);
    const int ocol = lane & 15;
    if (p == 0) {
#pragma unroll
        for (int f = 0; f < 16; ++f)
#pragma unroll
            for (int r = 0; r < 4; ++r)
                Q[(size_t)(orow + r) * 256 + f * 16 + ocol] = acc[f][r];
    } else {
        unsigned short* dstb = (p == 1) ? Kb : Vb;
#pragma unroll
        for (int f = 0; f < 16; ++f)
#pragma unroll
            for (int r = 0; r < 4; ++r)
                dstb[(size_t)(orow + r) * 256 + f * 16 + ocol] = f2bf(acc[f][r]);
    }
}

// ---------------------------------------------------------------- Vsum = column sums of V
__global__ __launch_bounds__(256) void vsum_partial(
    const unsigned short* __restrict__ Vb, float* __restrict__ partial)
{
    int b = blockIdx.x, t = threadIdx.x;
    float s = 0.0f;
    for (int r = 0; r < 64; ++r)
        s += bf2f(Vb[(size_t)(b * 64 + r) * 256 + t]);
    partial[b * 256 + t] = s;
}
__global__ __launch_bounds__(256) void vsum_final(
    const float* __restrict__ partial, float* __restrict__ Vsum)
{
    int t = threadIdx.x;
    float s = 0.0f;
    for (int b = 0; b < 128; ++b) s += partial[b * 256 + t];
    Vsum[t] = s;
}

// ---------------------------------------------------------------- fused scan+gather per (row, quadrant)
// 32768 blocks x 256 threads. Block b: row i=b>>2, quadrant q=b&3 (cols
// q*2048..+2048). Wave w owns a 512-col sub-slice: nt-load 2 KB of adj,
// ballot-compact (~5 edges) into its own LDS segment, then the proven bf16
// edge loop (16-lane group per edge dot; full-wave axpy of 4 V rows/round).
// Emits quadrant partial: 256-dim num (bf16) + den (f32).
__global__ __launch_bounds__(256) void attn_oct(
    const float* __restrict__ adj, const float* __restrict__ Q,
    const unsigned short* __restrict__ Kb, const unsigned short* __restrict__ Vb,
    unsigned short* __restrict__ pnum, float* __restrict__ pden)
{
    __shared__ unsigned short s_idx[4][CAP];
    __shared__ float s_q[256];
    __shared__ float s_pacc[4][256];
    __shared__ float s_den[4];

    const int bq   = blockIdx.x & 3;
    const int i    = blockIdx.x >> 2;
    const int tid  = threadIdx.x;
    const int lane = tid & 63;
    const int w    = tid >> 6;
    const unsigned long long lt = (1ull << lane) - 1ull;

    // stage Q row via LDS (nt: single use per XCD, keep out of L2)
    s_q[tid] = __builtin_nontemporal_load(Q + (size_t)i * DIM + tid);

    // adj sub-slice: 512 floats = 2 x f32x4 per lane (nontemporal)
    const f32x4* arow4 = (const f32x4*)(adj + (size_t)i * NN + bq * 2048 + w * 512);
    f32x4 av0 = __builtin_nontemporal_load(arow4 + lane);
    f32x4 av1 = __builtin_nontemporal_load(arow4 + 64 + lane);

    const int jbase = bq * 2048 + w * 512;
    int off = 0;
#pragma unroll
    for (int c = 0; c < 4; ++c) {
        bool nz = (av0[c] != 0.0f);
        unsigned long long m = __ballot(nz);
        if (nz) s_idx[w][off + __popcll(m & lt)] = (unsigned short)(jbase + lane * 4 + c);
        off += __popcll(m);
    }
#pragma unroll
    for (int c = 0; c < 4; ++c) {
        bool nz = (av1[c] != 0.0f);
        unsigned long long m = __ballot(nz);
        if (nz) s_idx[w][off + __popcll(m & lt)] = (unsigned short)(jbase + 256 + lane * 4 + c);
        off += __popcll(m);
    }
    const int cnt = off;                      // wave-uniform

    __syncthreads();                          // s_q ready (also covers s_idx, same-wave anyway)

    const int qo = (lane & 15) * 16;
    f32x4 q0 = *(const f32x4*)(&s_q[qo]);
    f32x4 q1 = *(const f32x4*)(&s_q[qo + 4]);
    f32x4 q2 = *(const f32x4*)(&s_q[qo + 8]);
    f32x4 q3 = *(const f32x4*)(&s_q[qo + 12]);

    const int g = lane >> 4;
    float acc0 = 0.f, acc1 = 0.f, acc2 = 0.f, acc3 = 0.f, den = 0.f;
    const int rounds = (cnt + 3) >> 2;

#pragma unroll 2
    for (int r = 0; r < rounds; ++r) {
        const int kb0 = r * 4;
        int jg0 = (kb0 + 0 < cnt) ? (int)s_idx[w][kb0 + 0] : 0;
        int jg1 = (kb0 + 1 < cnt) ? (int)s_idx[w][kb0 + 1] : 0;
        int jg2 = (kb0 + 2 < cnt) ? (int)s_idx[w][kb0 + 2] : 0;
        int jg3 = (kb0 + 3 < cnt) ? (int)s_idx[w][kb0 + 3] : 0;

        const bool myv = (kb0 + g) < cnt;
        const int  myj = (g == 0) ? jg0 : (g == 1) ? jg1 : (g == 2) ? jg2 : jg3;

        const u32x4* kp = (const u32x4*)(Kb + (size_t)myj * DIM + (lane & 15) * 16);
        u32x4 ka = kp[0];
        u32x4 kc = kp[1];

        ushort4 v0 = *(const ushort4*)(Vb + (size_t)jg0 * DIM + lane * 4);
        ushort4 v1 = *(const ushort4*)(Vb + (size_t)jg1 * DIM + lane * 4);
        ushort4 v2 = *(const ushort4*)(Vb + (size_t)jg2 * DIM + lane * 4);
        ushort4 v3 = *(const ushort4*)(Vb + (size_t)jg3 * DIM + lane * 4);

        float d0 = q0[0] * dw_lo(ka[0]);
        float d1 = q0[1] * dw_hi(ka[0]);
        float d2 = q0[2] * dw_lo(ka[1]);
        float d3 = q0[3] * dw_hi(ka[1]);
        d0 = fmaf(q1[0], dw_lo(ka[2]), d0);
        d1 = fmaf(q1[1], dw_hi(ka[2]), d1);
        d2 = fmaf(q1[2], dw_lo(ka[3]), d2);
        d3 = fmaf(q1[3], dw_hi(ka[3]), d3);
        d0 = fmaf(q2[0], dw_lo(kc[0]), d0);
        d1 = fmaf(q2[1], dw_hi(kc[0]), d1);
        d2 = fmaf(q2[2], dw_lo(kc[1]), d2);
        d3 = fmaf(q2[3], dw_hi(kc[1]), d3);
        d0 = fmaf(q3[0], dw_lo(kc[2]), d0);
        d1 = fmaf(q3[1], dw_hi(kc[2]), d1);
        d2 = fmaf(q3[2], dw_lo(kc[3]), d2);
        d3 = fmaf(q3[3], dw_hi(kc[3]), d3);
        float d = (d0 + d1) + (d2 + d3);

        d += __shfl_xor(d, 1);
        d += __shfl_xor(d, 2);
        d += __shfl_xor(d, 4);
        d += __shfl_xor(d, 8);

        float e = myv ? (__expf(SCALE * d) - 1.0f) : 0.0f;

        float e0 = __shfl(e, 0);
        float e1 = __shfl(e, 16);
        float e2 = __shfl(e, 32);
        float e3 = __shfl(e, 48);
        den += (e0 + e1) + (e2 + e3);

        acc0 = fmaf(e0, bf2f(v0.x), acc0); acc1 = fmaf(e0, bf2f(v0.y), acc1);
        acc2 = fmaf(e0, bf2f(v0.z), acc2); acc3 = fmaf(e0, bf2f(v0.w), acc3);
        acc0 = fmaf(e1, bf2f(v1.x), acc0); acc1 = fmaf(e1, bf2f(v1.y), acc1);
        acc2 = fmaf(e1, bf2f(v1.z), acc2); acc3 = fmaf(e1, bf2f(v1.w), acc3);
        acc0 = fmaf(e2, bf2f(v2.x), acc0); acc1 = fmaf(e2, bf2f(v2.y), acc1);
        acc2 = fmaf(e2, bf2f(v2.z), acc2); acc3 = fmaf(e2, bf2f(v2.w), acc3);
        acc0 = fmaf(e3, bf2f(v3.x), acc0); acc1 = fmaf(e3, bf2f(v3.y), acc1);
        acc2 = fmaf(e3, bf2f(v3.z), acc2); acc3 = fmaf(e3, bf2f(v3.w), acc3);
    }

    // cross-wave reduction -> quadrant partial
    f32x4 accv = {acc0, acc1, acc2, acc3};
    *(f32x4*)(&s_pacc[w][lane * 4]) = accv;
    if (lane == 0) s_den[w] = den;
    __syncthreads();

    float a = (s_pacc[0][tid] + s_pacc[1][tid]) + (s_pacc[2][tid] + s_pacc[3][tid]);
    __builtin_nontemporal_store(f2bf(a), pnum + (size_t)blockIdx.x * 256 + tid);
    if (tid == 0) {
        float dn = (s_den[0] + s_den[1]) + (s_den[2] + s_den[3]);
        pden[blockIdx.x] = dn;
    }
}

// ---------------------------------------------------------------- finalize: sum 4 quadrant partials
__global__ __launch_bounds__(256) void finalize(
    const unsigned short* __restrict__ pnum, const float* __restrict__ pden,
    const float* __restrict__ Vsum, float* __restrict__ out)
{
    const int i = blockIdx.x, t = threadIdx.x;
    float num = 0.0f, den = 0.0f;
#pragma unroll
    for (int x = 0; x < 4; ++x) {
        num += bf2f(pnum[(size_t)(i * 4 + x) * 256 + t]);
        den += pden[i * 4 + x];
    }
    out[(size_t)i * DIM + t] = (Vsum[t] + num) / (8192.0f + den);
}

// ---------------------------------------------------------------- host
extern "C" void kernel_launch(void* const* d_in, const int* in_sizes, int n_in,
                              void* d_out, int out_size, void* d_ws, size_t ws_size,
                              hipStream_t stream)
{
    const float* adj = (const float*)d_in[0];
    const float* h   = (const float*)d_in[1];
    const float* Wq  = (const float*)d_in[2];
    const float* Wk  = (const float*)d_in[3];
    const float* Wv  = (const float*)d_in[4];
    float* out = (float*)d_out;

    char* ws = (char*)d_ws;
    size_t off = 0;
    unsigned short* p_hbf = (unsigned short*)(ws + off); off += (size_t)NN * DIM * 2;
    unsigned short* p_wbf = (unsigned short*)(ws + off); off += (size_t)3 * DIM * DIM * 2;
    off = (off + 1023) & ~(size_t)1023;
    float*          p_Q   = (float*)(ws + off);          off += (size_t)NN * DIM * 4;
    unsigned short* p_Kb  = (unsigned short*)(ws + off); off += (size_t)NN * DIM * 2;
    unsigned short* p_Vb  = (unsigned short*)(ws + off); off += (size_t)NN * DIM * 2;
    float*          p_par = (float*)(ws + off);          off += (size_t)128 * DIM * 4;
    float*          p_vs  = (float*)(ws + off);          off += DIM * 4;
    unsigned short* p_pn  = (unsigned short*)(ws + off); off += (size_t)NN * 4 * 256 * 2;  // 16.8 MB
    float*          p_pd  = (float*)(ws + off);          off += (size_t)NN * 4 * 4;
    (void)ws_size; (void)in_sizes; (void)n_in; (void)out_size;

    prep_kernel<<<2240, 256, 0, stream>>>(h, Wq, Wk, Wv, p_hbf, p_wbf);
    proj_gemm<<<dim3(128, 3), 256, 0, stream>>>(p_hbf, p_wbf, p_Q, p_Kb, p_Vb);
    vsum_partial<<<128, 256, 0, stream>>>(p_Vb, p_par);
    vsum_final<<<1, 256, 0, stream>>>(p_par, p_vs);
    attn_oct<<<NN * 4, 256, 0, stream>>>(adj, p_Q, p_Kb, p_Vb, p_pn, p_pd);
    finalize<<<NN, 256, 0, stream>>>(p_pn, p_pd, p_vs, out);
}